// Round 5
// baseline (234.919 us; speedup 1.0000x reference)
//
#include <hip/hip_runtime.h>

#define B   64
#define K   512
#define C   4
#define NL  5
#define NCH 32          // 32 chunks x 16 rows = 512
#define BK  (B*K)

typedef _Float16 half_t;
typedef _Float16 half8 __attribute__((ext_vector_type(8)));
typedef float    f4    __attribute__((ext_vector_type(4)));

// ---------------------------------------------------------------------------
// Precompute: Habs2 = h_re^2 + h_im^2 as fp16 (33.5 MB, L3-resident) + the
// diagonal |H_bkk|^2 + v-state init. 16 elements/thread: 8 NT float4 loads
// in flight per lane for latency hiding; h_re/h_im are read-once (NT keeps
// L3 space for habs, which is re-read 5x).
// ---------------------------------------------------------------------------
__global__ __launch_bounds__(256) void k_pre(const float* __restrict__ hre,
                                             const float* __restrict__ him,
                                             const float* __restrict__ vre,
                                             const float* __restrict__ vim,
                                             half_t* __restrict__ habs,
                                             float* __restrict__ dabs2,
                                             float2* __restrict__ vstate,
                                             float* __restrict__ xsq) {
    size_t t    = (size_t)blockIdx.x * blockDim.x + threadIdx.x;
    size_t base = t * 16;
    const f4* r4 = (const f4*)(hre + base);
    const f4* i4 = (const f4*)(him + base);
    f4 r[4], im[4];
#pragma unroll
    for (int q = 0; q < 4; ++q) r[q]  = __builtin_nontemporal_load(r4 + q);
#pragma unroll
    for (int q = 0; q < 4; ++q) im[q] = __builtin_nontemporal_load(i4 + q);

    float s[16];
#pragma unroll
    for (int q = 0; q < 4; ++q) {
        s[q * 4 + 0] = r[q].x * r[q].x + im[q].x * im[q].x;
        s[q * 4 + 1] = r[q].y * r[q].y + im[q].y * im[q].y;
        s[q * 4 + 2] = r[q].z * r[q].z + im[q].z * im[q].z;
        s[q * 4 + 3] = r[q].w * r[q].w + im[q].w * im[q].w;
    }
    half8 h0, h1;
#pragma unroll
    for (int q = 0; q < 8; ++q) { h0[q] = (_Float16)s[q]; h1[q] = (_Float16)s[q + 8]; }
    *(half8*)(habs + base)     = h0;
    *(half8*)(habs + base + 8) = h1;

    // diagonal: 16-elem chunk never crosses a row (512 % 16 == 0)
    int col0 = (int)(base & (K - 1));
    int row  = (int)((base >> 9) & (K - 1));
    if (row >= col0 && row < col0 + 16) {
        size_t b = base >> 18;
        dabs2[b * K + row] = s[row - col0];
    }

    // v-state init (first BK threads)
    if (t < BK) {
        float a = vre[t], b = vim[t];
        vstate[t] = make_float2(a, b);
        xsq[t]    = a * a + b * b;
    }
}

// ---------------------------------------------------------------------------
// Fused cov + transposed-matvec for one 16-row chunk of one batch.
// Block (b, jc): 4 waves, wave w owns rows j0=jc*16+w*4 .. +3.
// Phase 1: lane owns 8 consecutive cols (16 B fp16 load per row); row-sum via
//   butterfly shuffle; lanes 0-3 compute the per-row u/w algebra in parallel:
//     A = |d|^2 xsq ; w = cov/(cov-A) (real!) ; vtilde = (|d|^2 w/cov) v
//     ulvec = A w / cov^2   -> LDS only
// Phase 2: REUSE the phase-1 register fragments (same lane->column mapping!)
//   for the transposed matvec over this chunk; cross-wave sum via 8 KB LDS;
//   write ulpart[jc][b][:] coalesced.
// habs is read exactly ONCE per layer. Grid: B*NCH = 2048 blocks (8/CU).
// ---------------------------------------------------------------------------
__global__ __launch_bounds__(256) void k_layer1(const half_t* __restrict__ habs,
                                                const float* __restrict__ xsq,
                                                const float* __restrict__ noise,
                                                const float* __restrict__ dabs2,
                                                const float2* __restrict__ vstate,
                                                float2* __restrict__ vtilde,
                                                float* __restrict__ ulpart) {
    int lane = threadIdx.x & 63;
    int wv   = threadIdx.x >> 6;
    int b    = blockIdx.x >> 5;
    int jc   = blockIdx.x & (NCH - 1);
    int j0   = jc * 16 + wv * 4;

    __shared__ float uls[16];
    __shared__ float part[4][K];

    const float4* x4 = (const float4*)(xsq + b * K);
    float4 xa = x4[lane * 2];
    float4 xb = x4[lane * 2 + 1];

    half8 h[4];
    const half8* rp = (const half8*)(habs + ((size_t)b * K + j0) * K);
#pragma unroll
    for (int r = 0; r < 4; ++r) h[r] = rp[r * (K / 8) + lane];

    float rs[4];
#pragma unroll
    for (int r = 0; r < 4; ++r) {
        float acc = (float)h[r][0] * xa.x + (float)h[r][1] * xa.y +
                    (float)h[r][2] * xa.z + (float)h[r][3] * xa.w +
                    (float)h[r][4] * xb.x + (float)h[r][5] * xb.y +
                    (float)h[r][6] * xb.z + (float)h[r][7] * xb.w;
#pragma unroll
        for (int off = 32; off; off >>= 1) acc += __shfl_xor(acc, off, 64);
        rs[r] = acc;   // all lanes hold the row sum
    }

    if (lane < 4) {
        float s  = (lane == 0) ? rs[0] : (lane == 1) ? rs[1]
                 : (lane == 2) ? rs[2] : rs[3];
        int bj   = b * K + j0 + lane;
        float cov = s + noise[bj];
        float A   = dabs2[bj] * xsq[bj];
        float w   = cov / (cov - A);
        float sc  = dabs2[bj] * w / cov;
        float2 vv = vstate[bj];
        vtilde[bj] = make_float2(sc * vv.x, sc * vv.y);
        uls[wv * 4 + lane] = A * w / (cov * cov);
    }
    __syncthreads();

    float u0 = uls[wv * 4 + 0];
    float u1 = uls[wv * 4 + 1];
    float u2 = uls[wv * 4 + 2];
    float u3 = uls[wv * 4 + 3];
    float* pw = &part[wv][lane * 8];
#pragma unroll
    for (int q = 0; q < 8; ++q) {
        pw[q] = (float)h[0][q] * u0 + (float)h[1][q] * u1 +
                (float)h[2][q] * u2 + (float)h[3][q] * u3;
    }
    __syncthreads();

    // 256 threads x 2 consecutive cols: sum 4 wave-partials, write coalesced
    int c = threadIdx.x * 2;
    float s0 = part[0][c]     + part[1][c]     + part[2][c]     + part[3][c];
    float s1 = part[0][c + 1] + part[1][c + 1] + part[2][c + 1] + part[3][c + 1];
    ((float2*)(ulpart + ((size_t)jc * B + b) * K))[threadIdx.x] = make_float2(s0, s1);
}

// ---------------------------------------------------------------------------
// K3: finish — sum 32 coalesced partial streams, mu/ula, ar/dl mix, CReLU,
// rc recombine, power correction; write new state + layer output.
// ---------------------------------------------------------------------------
__global__ __launch_bounds__(128) void k_fin(const float* __restrict__ ulpart,
                                             const float2* __restrict__ vtilde,
                                             const float* __restrict__ maxpow,
                                             const float* __restrict__ ar_re,
                                             const float* __restrict__ ar_im,
                                             const float* __restrict__ dl_re,
                                             const float* __restrict__ dl_im,
                                             const float* __restrict__ rc_re,
                                             const float* __restrict__ rc_im,
                                             float2* __restrict__ vstate,
                                             float* __restrict__ xsq,
                                             float* __restrict__ out) {
    int t = blockIdx.x * blockDim.x + threadIdx.x;
    float ul = 0.f;
#pragma unroll
    for (int jc = 0; jc < NCH; ++jc) ul += ulpart[jc * BK + t];

    float2 vt = vtilde[t];
    float  p  = maxpow[t];
    float avt = sqrtf(vt.x * vt.x + vt.y * vt.y);
    float mu  = fmaxf(avt / sqrtf(p) - ul, 0.f);
    float ula = ul + mu;
    float inv = 1.f / ula;

    float ax = 0.f, ay = 0.f;
#pragma unroll
    for (int c = 0; c < C; ++c) {
        float gre = ar_re[c] * inv + dl_re[c];
        float gim = ar_im[c] * inv + dl_im[c];
        float zre = vt.x * gre - vt.y * gim;   // vt * g
        float zim = vt.x * gim + vt.y * gre;
        zre = fmaxf(zre, 0.f);                 // CReLU
        zim = fmaxf(zim, 0.f);
        ax += zre * rc_re[c] - zim * rc_im[c]; // += z * rc
        ay += zre * rc_im[c] + zim * rc_re[c];
    }
    float n2   = ax * ax + ay * ay;
    float cur  = fmaxf(p, n2);
    float corr = fminf(sqrtf(p / cur), 1.f);
    ax *= corr;
    ay *= corr;
    vstate[t] = make_float2(ax, ay);
    xsq[t]    = ax * ax + ay * ay;
    out[2 * t]     = ax;
    out[2 * t + 1] = ay;
}

// ---------------------------------------------------------------------------
extern "C" void kernel_launch(void* const* d_in, const int* in_sizes, int n_in,
                              void* d_out, int out_size, void* d_ws, size_t ws_size,
                              hipStream_t stream) {
    const float* hre   = (const float*)d_in[0];
    const float* him   = (const float*)d_in[1];
    const float* noise = (const float*)d_in[2];
    const float* mp    = (const float*)d_in[3];
    const float* vre   = (const float*)d_in[4];
    const float* vim   = (const float*)d_in[5];
    const float* ar_re = (const float*)d_in[6];
    const float* ar_im = (const float*)d_in[7];
    const float* dl_re = (const float*)d_in[8];
    const float* dl_im = (const float*)d_in[9];
    const float* rc_re = (const float*)d_in[10];
    const float* rc_im = (const float*)d_in[11];
    float* out = (float*)d_out;

    char*   ws     = (char*)d_ws;
    size_t  off    = 0;
    half_t* habs   = (half_t*)(ws + off); off += (size_t)BK * K * 2;  // 33.5 MB
    float*  dabs2  = (float*) (ws + off); off += (size_t)BK * 4;
    float2* vstate = (float2*)(ws + off); off += (size_t)BK * 8;
    float*  xsq    = (float*) (ws + off); off += (size_t)BK * 4;
    float2* vtilde = (float2*)(ws + off); off += (size_t)BK * 8;
    float*  ulpart = (float*) (ws + off); off += (size_t)NCH * BK * 4; // 4.2 MB

    // 16.78M elems / 16 per thread / 256 per block = 4096 blocks
    k_pre<<<(size_t)BK * K / 16 / 256, 256, 0, stream>>>(hre, him, vre, vim,
                                                         habs, dabs2, vstate, xsq);

    for (int l = 0; l < NL; ++l) {
        k_layer1<<<B * NCH, 256, 0, stream>>>(habs, xsq, noise, dabs2, vstate,
                                              vtilde, ulpart);
        k_fin<<<BK / 128, 128, 0, stream>>>(ulpart, vtilde, mp,
                                            ar_re, ar_im, dl_re, dl_im,
                                            rc_re, rc_im,
                                            vstate, xsq,
                                            out + (size_t)l * BK * 2);
    }
}

// Round 6
// 222.379 us; speedup vs baseline: 1.0564x; 1.0564x over previous
//
#include <hip/hip_runtime.h>

#define B   64
#define K   512
#define C   4
#define NL  5
#define NCH 32           // chunks for layers 2..5 (16 rows each)
#define NCH1 128         // chunks for fused layer 1 (4 rows each)
#define BK  (B*K)

typedef _Float16 half_t;
typedef _Float16 half8 __attribute__((ext_vector_type(8)));
typedef float    f4    __attribute__((ext_vector_type(4)));

// ---------------------------------------------------------------------------
// Init: v state (float2) and xsq = |v|^2. Must run before k_pre_l1 (it
// consumes xsq).
// ---------------------------------------------------------------------------
__global__ __launch_bounds__(256) void k_init(const float* __restrict__ vre,
                                              const float* __restrict__ vim,
                                              float2* __restrict__ vstate,
                                              float* __restrict__ xsq) {
    int t = blockIdx.x * blockDim.x + threadIdx.x;
    float a = vre[t], b = vim[t];
    vstate[t] = make_float2(a, b);
    xsq[t]    = a * a + b * b;
}

// ---------------------------------------------------------------------------
// Fused precompute + LAYER 1. Block = 2048 consecutive elements = 4 complete
// rows of one batch; wave w owns row (blockIdx&127)*4 + w, lane owns 8
// consecutive cols. Does:
//   - Habs2 = re^2+im^2 -> fp16 habs (temporal store; L3-resident for l2..5)
//   - dabs2 diag extraction (and in-wave fp32 diag via shuffle for layer 1)
//   - layer-1 phase 1: cov row-dot (fp32 fragments), u/w algebra, vtilde
//   - layer-1 phase 2: fragment * ulvec, 4-wave LDS combine, ulpart128 write
// h_re/h_im read ONCE (NT); habs never re-read for layer 1.
// ---------------------------------------------------------------------------
__global__ __launch_bounds__(256) void k_pre_l1(const float* __restrict__ hre,
                                                const float* __restrict__ him,
                                                const float* __restrict__ xsq,
                                                const float* __restrict__ noise,
                                                const float2* __restrict__ vstate,
                                                half_t* __restrict__ habs,
                                                float* __restrict__ dabs2,
                                                float2* __restrict__ vtilde,
                                                float* __restrict__ ulpart) {
    int tid  = threadIdx.x;
    int lane = tid & 63;
    int wv   = tid >> 6;
    size_t base = (size_t)blockIdx.x * 2048 + (size_t)tid * 8;
    size_t b    = base >> 18;               // batch
    int    j    = (int)((base >> 9) & (K - 1)); // row (wave-uniform)
    int    jc   = blockIdx.x & (NCH1 - 1);  // 4-row chunk index

    const f4* r4 = (const f4*)(hre + base);
    const f4* i4 = (const f4*)(him + base);
    f4 r0 = __builtin_nontemporal_load(r4);
    f4 r1 = __builtin_nontemporal_load(r4 + 1);
    f4 i0 = __builtin_nontemporal_load(i4);
    f4 i1 = __builtin_nontemporal_load(i4 + 1);

    float s[8];
    s[0] = r0.x * r0.x + i0.x * i0.x;
    s[1] = r0.y * r0.y + i0.y * i0.y;
    s[2] = r0.z * r0.z + i0.z * i0.z;
    s[3] = r0.w * r0.w + i0.w * i0.w;
    s[4] = r1.x * r1.x + i1.x * i1.x;
    s[5] = r1.y * r1.y + i1.y * i1.y;
    s[6] = r1.z * r1.z + i1.z * i1.z;
    s[7] = r1.w * r1.w + i1.w * i1.w;

    half8 h;
#pragma unroll
    for (int q = 0; q < 8; ++q) h[q] = (_Float16)s[q];
    *(half8*)(habs + base) = h;

    // fp32 diagonal |H_jj|^2 for this row, in-wave: lane j>>3 holds it
    float cand = s[j & 7];
    float d2   = __shfl(cand, j >> 3, 64);
    if (lane == (j >> 3)) dabs2[b * K + j] = cand;

    // ---- layer-1 phase 1: cov dot with xsq[b,:] ----
    const f4* xq = (const f4*)(xsq + b * K);
    f4 xa = xq[lane * 2];
    f4 xb = xq[lane * 2 + 1];
    float acc = s[0] * xa.x + s[1] * xa.y + s[2] * xa.z + s[3] * xa.w +
                s[4] * xb.x + s[5] * xb.y + s[6] * xb.z + s[7] * xb.w;
#pragma unroll
    for (int off = 32; off; off >>= 1) acc += __shfl_xor(acc, off, 64);

    int bj = (int)(b * K) + j;
    float ulv;
    if (lane == 0) {
        float cov = acc + noise[bj];
        float A   = d2 * xsq[bj];
        float w   = cov / (cov - A);
        float sc  = d2 * w / cov;
        float2 vv = vstate[bj];
        vtilde[bj] = make_float2(sc * vv.x, sc * vv.y);
        ulv = A * w / (cov * cov);
    }
    ulv = __shfl(ulv, 0, 64);

    // ---- layer-1 phase 2: transposed-matvec partial for this 4-row chunk ----
    __shared__ float part[4][K];
    float* pw = &part[wv][lane * 8];
#pragma unroll
    for (int q = 0; q < 8; ++q) pw[q] = s[q] * ulv;
    __syncthreads();

    int c = tid * 2;
    float s0 = part[0][c]     + part[1][c]     + part[2][c]     + part[3][c];
    float s1 = part[0][c + 1] + part[1][c + 1] + part[2][c + 1] + part[3][c + 1];
    ((float2*)(ulpart + ((size_t)jc * B + b) * K))[tid] = make_float2(s0, s1);
}

// ---------------------------------------------------------------------------
// Fused cov + transposed-matvec for one 16-row chunk (layers 2..5).
// Identical structure to before: habs fp16 read once per layer.
// ---------------------------------------------------------------------------
__global__ __launch_bounds__(256) void k_layer1(const half_t* __restrict__ habs,
                                                const float* __restrict__ xsq,
                                                const float* __restrict__ noise,
                                                const float* __restrict__ dabs2,
                                                const float2* __restrict__ vstate,
                                                float2* __restrict__ vtilde,
                                                float* __restrict__ ulpart) {
    int lane = threadIdx.x & 63;
    int wv   = threadIdx.x >> 6;
    int b    = blockIdx.x >> 5;
    int jc   = blockIdx.x & (NCH - 1);
    int j0   = jc * 16 + wv * 4;

    __shared__ float uls[16];
    __shared__ float part[4][K];

    const float4* x4 = (const float4*)(xsq + b * K);
    float4 xa = x4[lane * 2];
    float4 xb = x4[lane * 2 + 1];

    half8 h[4];
    const half8* rp = (const half8*)(habs + ((size_t)b * K + j0) * K);
#pragma unroll
    for (int r = 0; r < 4; ++r) h[r] = rp[r * (K / 8) + lane];

    float rs[4];
#pragma unroll
    for (int r = 0; r < 4; ++r) {
        float acc = (float)h[r][0] * xa.x + (float)h[r][1] * xa.y +
                    (float)h[r][2] * xa.z + (float)h[r][3] * xa.w +
                    (float)h[r][4] * xb.x + (float)h[r][5] * xb.y +
                    (float)h[r][6] * xb.z + (float)h[r][7] * xb.w;
#pragma unroll
        for (int off = 32; off; off >>= 1) acc += __shfl_xor(acc, off, 64);
        rs[r] = acc;
    }

    if (lane < 4) {
        float s  = (lane == 0) ? rs[0] : (lane == 1) ? rs[1]
                 : (lane == 2) ? rs[2] : rs[3];
        int bj   = b * K + j0 + lane;
        float cov = s + noise[bj];
        float A   = dabs2[bj] * xsq[bj];
        float w   = cov / (cov - A);
        float sc  = dabs2[bj] * w / cov;
        float2 vv = vstate[bj];
        vtilde[bj] = make_float2(sc * vv.x, sc * vv.y);
        uls[wv * 4 + lane] = A * w / (cov * cov);
    }
    __syncthreads();

    float u0 = uls[wv * 4 + 0];
    float u1 = uls[wv * 4 + 1];
    float u2 = uls[wv * 4 + 2];
    float u3 = uls[wv * 4 + 3];
    float* pw = &part[wv][lane * 8];
#pragma unroll
    for (int q = 0; q < 8; ++q) {
        pw[q] = (float)h[0][q] * u0 + (float)h[1][q] * u1 +
                (float)h[2][q] * u2 + (float)h[3][q] * u3;
    }
    __syncthreads();

    int c = threadIdx.x * 2;
    float s0 = part[0][c]     + part[1][c]     + part[2][c]     + part[3][c];
    float s1 = part[0][c + 1] + part[1][c + 1] + part[2][c + 1] + part[3][c + 1];
    ((float2*)(ulpart + ((size_t)jc * B + b) * K))[threadIdx.x] = make_float2(s0, s1);
}

// ---------------------------------------------------------------------------
// Finish: sum NCHUNKS coalesced partial streams, mu/ula, ar/dl mix, CReLU,
// rc recombine, power correction; write new state + layer output.
// ---------------------------------------------------------------------------
template <int NCHUNKS>
__global__ __launch_bounds__(128) void k_fin(const float* __restrict__ ulpart,
                                             const float2* __restrict__ vtilde,
                                             const float* __restrict__ maxpow,
                                             const float* __restrict__ ar_re,
                                             const float* __restrict__ ar_im,
                                             const float* __restrict__ dl_re,
                                             const float* __restrict__ dl_im,
                                             const float* __restrict__ rc_re,
                                             const float* __restrict__ rc_im,
                                             float2* __restrict__ vstate,
                                             float* __restrict__ xsq,
                                             float* __restrict__ out) {
    int t = blockIdx.x * blockDim.x + threadIdx.x;
    float ul = 0.f;
#pragma unroll 16
    for (int jc = 0; jc < NCHUNKS; ++jc) ul += ulpart[(size_t)jc * BK + t];

    float2 vt = vtilde[t];
    float  p  = maxpow[t];
    float avt = sqrtf(vt.x * vt.x + vt.y * vt.y);
    float mu  = fmaxf(avt / sqrtf(p) - ul, 0.f);
    float ula = ul + mu;
    float inv = 1.f / ula;

    float ax = 0.f, ay = 0.f;
#pragma unroll
    for (int c = 0; c < C; ++c) {
        float gre = ar_re[c] * inv + dl_re[c];
        float gim = ar_im[c] * inv + dl_im[c];
        float zre = vt.x * gre - vt.y * gim;   // vt * g
        float zim = vt.x * gim + vt.y * gre;
        zre = fmaxf(zre, 0.f);                 // CReLU
        zim = fmaxf(zim, 0.f);
        ax += zre * rc_re[c] - zim * rc_im[c]; // += z * rc
        ay += zre * rc_im[c] + zim * rc_re[c];
    }
    float n2   = ax * ax + ay * ay;
    float cur  = fmaxf(p, n2);
    float corr = fminf(sqrtf(p / cur), 1.f);
    ax *= corr;
    ay *= corr;
    vstate[t] = make_float2(ax, ay);
    xsq[t]    = ax * ax + ay * ay;
    out[2 * t]     = ax;
    out[2 * t + 1] = ay;
}

// ---------------------------------------------------------------------------
extern "C" void kernel_launch(void* const* d_in, const int* in_sizes, int n_in,
                              void* d_out, int out_size, void* d_ws, size_t ws_size,
                              hipStream_t stream) {
    const float* hre   = (const float*)d_in[0];
    const float* him   = (const float*)d_in[1];
    const float* noise = (const float*)d_in[2];
    const float* mp    = (const float*)d_in[3];
    const float* vre   = (const float*)d_in[4];
    const float* vim   = (const float*)d_in[5];
    const float* ar_re = (const float*)d_in[6];
    const float* ar_im = (const float*)d_in[7];
    const float* dl_re = (const float*)d_in[8];
    const float* dl_im = (const float*)d_in[9];
    const float* rc_re = (const float*)d_in[10];
    const float* rc_im = (const float*)d_in[11];
    float* out = (float*)d_out;

    char*   ws     = (char*)d_ws;
    size_t  off    = 0;
    half_t* habs   = (half_t*)(ws + off); off += (size_t)BK * K * 2;   // 33.5 MB
    float*  dabs2  = (float*) (ws + off); off += (size_t)BK * 4;
    float2* vstate = (float2*)(ws + off); off += (size_t)BK * 8;
    float*  xsq    = (float*) (ws + off); off += (size_t)BK * 4;
    float2* vtilde = (float2*)(ws + off); off += (size_t)BK * 8;
    float*  ulpart = (float*) (ws + off); off += (size_t)NCH1 * BK * 4; // 16.8 MB

    k_init<<<BK / 256, 256, 0, stream>>>(vre, vim, vstate, xsq);
    // 16.78M elems / 8 per thread / 256 per block = 8192 blocks
    k_pre_l1<<<(size_t)BK * K / 8 / 256, 256, 0, stream>>>(hre, him, xsq, noise,
                                                           vstate, habs, dabs2,
                                                           vtilde, ulpart);
    k_fin<NCH1><<<BK / 128, 128, 0, stream>>>(ulpart, vtilde, mp,
                                              ar_re, ar_im, dl_re, dl_im,
                                              rc_re, rc_im, vstate, xsq, out);

    for (int l = 1; l < NL; ++l) {
        k_layer1<<<B * NCH, 256, 0, stream>>>(habs, xsq, noise, dabs2, vstate,
                                              vtilde, ulpart);
        k_fin<NCH><<<BK / 128, 128, 0, stream>>>(ulpart, vtilde, mp,
                                                 ar_re, ar_im, dl_re, dl_im,
                                                 rc_re, rc_im, vstate, xsq,
                                                 out + (size_t)l * BK * 2);
    }
}